// Round 1
// baseline (192.145 us; speedup 1.0000x reference)
//
#include <hip/hip_runtime.h>
#include <hip/hip_bf16.h>

typedef unsigned short u16;
typedef unsigned int u32;
typedef short s16x8 __attribute__((ext_vector_type(8)));
typedef float f32x4 __attribute__((ext_vector_type(4)));
typedef u32 u32x4 __attribute__((ext_vector_type(4)));

#define DEV static __device__ __forceinline__

DEV u16 bf16_rne(float f) {
  u32 u = __builtin_bit_cast(u32, f);
  u += 0x7fffu + ((u >> 16) & 1u);
  return (u16)(u >> 16);
}

DEV u32 pack2_bf16(float a, float b) {  // a -> low16, b -> high16 (both RNE)
  u32 ua = __builtin_bit_cast(u32, a);
  u32 ub = __builtin_bit_cast(u32, b);
  ua += 0x7fffu + ((ua >> 16) & 1u);
  ub += 0x7fffu + ((ub >> 16) & 1u);
  return (ua >> 16) | (ub & 0xffff0000u);
}

#define GLDS16(g, l)                                                           \
  __builtin_amdgcn_global_load_lds(                                           \
      (const __attribute__((address_space(1))) void*)(g),                     \
      (__attribute__((address_space(3))) void*)(l), 16, 0, 0)

// ---------------- convert fp32 -> bf16 (vectorized, G13) ----------------
__global__ void cvt_kernel(const float* __restrict__ src, u16* __restrict__ dst,
                           int n4) {
  int i = blockIdx.x * blockDim.x + threadIdx.x;
  if (i < n4) {
    float4 v = reinterpret_cast<const float4*>(src)[i];
    ushort4 o;
    o.x = bf16_rne(v.x);
    o.y = bf16_rne(v.y);
    o.z = bf16_rne(v.z);
    o.w = bf16_rne(v.w);
    reinterpret_cast<ushort4*>(dst)[i] = o;
  }
}

// ---------------- GEMM: C[M,N] = A[M,K] * W[N,K]^T + bias ----------------
// BM=128, BN=64, BK=64. 128 threads = 2 waves; each wave computes 64x64.
template <int OUT_BF16>
__global__ __launch_bounds__(128, 2) void gemm_bt(
    const u16* __restrict__ A, const u16* __restrict__ W,
    const float* __restrict__ bias, void* __restrict__ Cout, int M, int N,
    int K) {
  __shared__ __align__(16) u16 As[128 * 64];
  __shared__ __align__(16) u16 Ws[64 * 64];
  const int tid = threadIdx.x;
  const int lane = tid & 63;
  const int w = tid >> 6;
  const int l15 = lane & 15, l4 = lane >> 4;
  const int m0 = blockIdx.y * 128, n0 = blockIdx.x * 64;

  f32x4 acc[4][4] = {};
  float bv[4];
#pragma unroll
  for (int fc = 0; fc < 4; ++fc) bv[fc] = bias[n0 + fc * 16 + l15];

  for (int kt = 0; kt < K; kt += 64) {
    __syncthreads();  // protect previous iteration's LDS reads
#pragma unroll
    for (int i = 0; i < 8; ++i) {  // A tile: 128 rows x 64 k = 1024 x 16B
      const int ch = i * 128 + w * 64 + lane;
      const int row = ch >> 3, k8 = ch & 7;
      GLDS16(A + (size_t)(m0 + row) * K + kt + k8 * 8,
             As + (size_t)(i * 128 + w * 64) * 8);
    }
#pragma unroll
    for (int i = 0; i < 4; ++i) {  // W tile: 64 rows x 64 k = 512 x 16B
      const int ch = i * 128 + w * 64 + lane;
      const int row = ch >> 3, k8 = ch & 7;
      GLDS16(W + (size_t)(n0 + row) * K + kt + k8 * 8,
             Ws + (size_t)(i * 128 + w * 64) * 8);
    }
    __syncthreads();
#pragma unroll
    for (int ks = 0; ks < 2; ++ks) {
      s16x8 a[4], b[4];
#pragma unroll
      for (int f = 0; f < 4; ++f)
        a[f] = *(const s16x8*)(As + (w * 64 + f * 16 + l15) * 64 + ks * 32 +
                               l4 * 8);
#pragma unroll
      for (int f = 0; f < 4; ++f)
        b[f] =
            *(const s16x8*)(Ws + (f * 16 + l15) * 64 + ks * 32 + l4 * 8);
#pragma unroll
      for (int fr = 0; fr < 4; ++fr)
#pragma unroll
        for (int fc = 0; fc < 4; ++fc)
          acc[fr][fc] = __builtin_amdgcn_mfma_f32_16x16x32_bf16(
              a[fr], b[fc], acc[fr][fc], 0, 0, 0);
    }
  }

#pragma unroll
  for (int fr = 0; fr < 4; ++fr) {
    const int mrow = m0 + w * 64 + fr * 16 + l4 * 4;
#pragma unroll
    for (int fc = 0; fc < 4; ++fc) {
      const int ncol = n0 + fc * 16 + l15;
#pragma unroll
      for (int r = 0; r < 4; ++r) {
        const float v = acc[fr][fc][r] + bv[fc];
        if (OUT_BF16)
          ((u16*)Cout)[(size_t)(mrow + r) * N + ncol] = bf16_rne(v);
        else
          ((float*)Cout)[(size_t)(mrow + r) * N + ncol] = v;
      }
    }
  }
}

// ---------------- fused flash attention ----------------
// grid (S/128, H, B), 256 threads = 4 waves. Wave w owns q-cols [w*32, w*32+32).
// Computes S^T = mfma(K, Q) so q is lane-local (lane&15); P kept in registers
// and redistributed to B-operand layout by shuffles; ctx^T = mfma(V^T, P^T).
__global__ __launch_bounds__(256, 2) void attn_fused(
    const u16* __restrict__ qp, const u16* __restrict__ kp,
    const u16* __restrict__ vp, u16* __restrict__ ctx) {
  const int S = 2048, D = 1024, HD = 64;
  const int qt = blockIdx.x, h = blockIdx.y, b = blockIdx.z;
  const int tid = threadIdx.x, lane = tid & 63, w = tid >> 6;
  const int l15 = lane & 15, l4 = lane >> 4;

  // K tile [128 kv][64 d], 16B chunks swizzled: chunk col = d8 ^ (kv&7)
  __shared__ __align__(16) u16 Ks[128 * 64];
  // V^T tile [64 d][128 kv], chunk col = (kv>>3) ^ (d&7) ^ (d>>3)
  __shared__ __align__(16) u16 Vt[64 * 128];

  const size_t base = ((size_t)b * S) * D + (size_t)h * HD;

  // Q B-operand fragments: [fq][d-32-chunk]
  s16x8 qf[2][2];
#pragma unroll
  for (int fq = 0; fq < 2; ++fq)
#pragma unroll
    for (int kc = 0; kc < 2; ++kc) {
      const int q = qt * 128 + w * 32 + fq * 16 + l15;
      qf[fq][kc] = *(const s16x8*)(qp + base + (size_t)q * D + kc * 32 + l4 * 8);
    }

  f32x4 octx[4][2] = {};              // ctx^T acc: [fd][fq], row=d, col=q
  float m_run[2] = {-1e30f, -1e30f};  // running max (log2-domain)
  float l_run[2] = {0.f, 0.f};
  const float C1 = 0.125f * 1.44269504088896f;  // 1/sqrt(64) * log2(e)

  for (int kv0 = 0; kv0 < S; kv0 += 128) {
    __syncthreads();
    // ---- stage K tile (swizzled row-major) ----
#pragma unroll
    for (int i = 0; i < 4; ++i) {
      const int ch = i * 256 + tid;  // 0..1023 -> (kv, d8)
      const int kv = ch >> 3, d8 = ch & 7;
      s16x8 v = *(const s16x8*)(kp + base + (size_t)(kv0 + kv) * D + d8 * 8);
      *(s16x8*)((char*)Ks + kv * 128 + ((d8 ^ (kv & 7)) * 16)) = v;
    }
    // ---- stage V^T (transposed, swizzled; lane map chosen for bank spread)
#pragma unroll
    for (int i = 0; i < 4; ++i) {
      const int kv = i * 32 + w * 8 + (lane & 7);
      const int d8 = lane >> 3;
      s16x8 v = *(const s16x8*)(vp + base + (size_t)(kv0 + kv) * D + d8 * 8);
      const int kv8 = kv >> 3, kv7 = kv & 7;
#pragma unroll
      for (int j = 0; j < 8; ++j) {
        const int d = d8 * 8 + j;
        *(u16*)((char*)Vt + d * 256 + ((kv8 ^ (d & 7) ^ (d >> 3)) * 16) +
                kv7 * 2) = (u16)v[j];
      }
    }
    __syncthreads();

    // ---- scores^T: sc[fk][fq], row=kv, col=q ----
    f32x4 sc[8][2] = {};
#pragma unroll
    for (int ks = 0; ks < 2; ++ks) {
      s16x8 kfr[8];
#pragma unroll
      for (int fk = 0; fk < 8; ++fk) {
        const int kv = fk * 16 + l15;
        const int d8 = ks * 4 + l4;
        kfr[fk] = *(const s16x8*)((char*)Ks + kv * 128 +
                                  ((d8 ^ (kv & 7)) * 16));
      }
#pragma unroll
      for (int fk = 0; fk < 8; ++fk)
#pragma unroll
        for (int fq = 0; fq < 2; ++fq)
          sc[fk][fq] = __builtin_amdgcn_mfma_f32_16x16x32_bf16(
              kfr[fk], qf[fq][ks], sc[fk][fq], 0, 0, 0);
    }

    // ---- online softmax (log2 domain), P packed to bf16 in registers ----
    u32 pkA[2][8], pkB[2][8];
#pragma unroll
    for (int fq = 0; fq < 2; ++fq) {
      float mt = sc[0][fq][0];
#pragma unroll
      for (int fk = 0; fk < 8; ++fk)
#pragma unroll
        for (int r = 0; r < 4; ++r) mt = fmaxf(mt, sc[fk][fq][r]);
      mt = fmaxf(mt, __shfl_xor(mt, 16, 64));
      mt = fmaxf(mt, __shfl_xor(mt, 32, 64));
      mt *= C1;
      const float mnew = fmaxf(m_run[fq], mt);
      const float resc = __builtin_amdgcn_exp2f(m_run[fq] - mnew);
      m_run[fq] = mnew;
      float rsum = 0.f;
#pragma unroll
      for (int fk = 0; fk < 8; ++fk) {
        const float p0 = __builtin_amdgcn_exp2f(fmaf(sc[fk][fq][0], C1, -mnew));
        const float p1 = __builtin_amdgcn_exp2f(fmaf(sc[fk][fq][1], C1, -mnew));
        const float p2 = __builtin_amdgcn_exp2f(fmaf(sc[fk][fq][2], C1, -mnew));
        const float p3 = __builtin_amdgcn_exp2f(fmaf(sc[fk][fq][3], C1, -mnew));
        rsum += (p0 + p1) + (p2 + p3);
        pkA[fq][fk] = pack2_bf16(p0, p1);
        pkB[fq][fk] = pack2_bf16(p2, p3);
      }
      rsum += __shfl_xor(rsum, 16, 64);
      rsum += __shfl_xor(rsum, 32, 64);
      l_run[fq] = l_run[fq] * resc + rsum;
#pragma unroll
      for (int fd = 0; fd < 4; ++fd)
#pragma unroll
        for (int r = 0; r < 4; ++r) octx[fd][fq][r] *= resc;
    }

    // ---- PV: octx[fd][fq] += mfma(V^T frag, P^T B-frag) ----
#pragma unroll
    for (int c = 0; c < 4; ++c) {  // kv 32-chunk
      s16x8 pb[2];
#pragma unroll
      for (int fq = 0; fq < 2; ++fq) {
        u32x4 wvv;
#pragma unroll
        for (int jj = 0; jj < 4; ++jj) {
          const int src = ((l4 & 1) * 2 + (jj >> 1)) * 16 + l15;
          const u32 c0 = (jj & 1) ? pkB[fq][2 * c] : pkA[fq][2 * c];
          const u32 c1 = (jj & 1) ? pkB[fq][2 * c + 1] : pkA[fq][2 * c + 1];
          const u32 v0 = (u32)__shfl((int)c0, src, 64);
          const u32 v1 = (u32)__shfl((int)c1, src, 64);
          wvv[jj] = (l4 < 2) ? v0 : v1;
        }
        pb[fq] = __builtin_bit_cast(s16x8, wvv);
      }
#pragma unroll
      for (int fd = 0; fd < 4; ++fd) {
        const int d = fd * 16 + l15;
        const s16x8 vf = *(const s16x8*)((const char*)Vt + d * 256 +
                                         (((c * 4 + l4) ^ (d & 7) ^ (d >> 3)) *
                                          16));
        octx[fd][0] = __builtin_amdgcn_mfma_f32_16x16x32_bf16(vf, pb[0],
                                                              octx[fd][0], 0,
                                                              0, 0);
        octx[fd][1] = __builtin_amdgcn_mfma_f32_16x16x32_bf16(vf, pb[1],
                                                              octx[fd][1], 0,
                                                              0, 0);
      }
    }
  }

  // ---- finalize: ctx[q][h*64+d] = octx^T / l ----
#pragma unroll
  for (int fq = 0; fq < 2; ++fq) {
    const float inv = 1.f / l_run[fq];
    const int q = qt * 128 + w * 32 + fq * 16 + l15;
#pragma unroll
    for (int fd = 0; fd < 4; ++fd) {
      ushort4 o;
      o.x = bf16_rne(octx[fd][fq][0] * inv);
      o.y = bf16_rne(octx[fd][fq][1] * inv);
      o.z = bf16_rne(octx[fd][fq][2] * inv);
      o.w = bf16_rne(octx[fd][fq][3] * inv);
      *reinterpret_cast<ushort4*>(ctx + base + (size_t)q * D + fd * 16 +
                                  l4 * 4) = o;
    }
  }
}

// ---------------- launcher ----------------
extern "C" void kernel_launch(void* const* d_in, const int* in_sizes, int n_in,
                              void* d_out, int out_size, void* d_ws,
                              size_t ws_size, hipStream_t stream) {
  (void)in_sizes; (void)n_in; (void)out_size; (void)ws_size;
  const float* Q = (const float*)d_in[0];
  const float* K = (const float*)d_in[1];
  const float* V = (const float*)d_in[2];
  const float* Wq = (const float*)d_in[3];
  const float* bq = (const float*)d_in[4];
  const float* Wk = (const float*)d_in[5];
  const float* bk = (const float*)d_in[6];
  const float* Wv = (const float*)d_in[7];
  const float* bv = (const float*)d_in[8];
  const float* Wo = (const float*)d_in[9];
  const float* bo = (const float*)d_in[10];

  const int B = 2, S = 2048, D = 1024, H = 16;
  const int M = B * S;                  // 4096
  const size_t NE = (size_t)M * D;      // 4M elems
  const size_t WE = (size_t)D * D;      // 1M elems

  u16* B0 = (u16*)d_ws;     // Qb -> then kp
  u16* B1 = B0 + NE;        // Kb -> then vp
  u16* B2 = B1 + NE;        // Vb -> then ctx
  u16* B3 = B2 + NE;        // qp
  u16* Wqb = B3 + NE;
  u16* Wkb = Wqb + WE;
  u16* Wvb = Wkb + WE;
  u16* Wob = Wvb + WE;

  {
    const int n4 = (int)(NE / 4), nb = (n4 + 255) / 256;
    cvt_kernel<<<nb, 256, 0, stream>>>(Q, B0, n4);
    cvt_kernel<<<nb, 256, 0, stream>>>(K, B1, n4);
    cvt_kernel<<<nb, 256, 0, stream>>>(V, B2, n4);
    const int w4 = (int)(WE / 4), wb = (w4 + 255) / 256;
    cvt_kernel<<<wb, 256, 0, stream>>>(Wq, Wqb, w4);
    cvt_kernel<<<wb, 256, 0, stream>>>(Wk, Wkb, w4);
    cvt_kernel<<<wb, 256, 0, stream>>>(Wv, Wvb, w4);
    cvt_kernel<<<wb, 256, 0, stream>>>(Wo, Wob, w4);
  }

  dim3 gg(D / 64, M / 128);  // (16, 32)
  gemm_bt<1><<<gg, 128, 0, stream>>>(B0, Wqb, bq, B3, M, D, D);  // qp
  gemm_bt<1><<<gg, 128, 0, stream>>>(B1, Wkb, bk, B0, M, D, D);  // kp
  gemm_bt<1><<<gg, 128, 0, stream>>>(B2, Wvb, bv, B1, M, D, D);  // vp

  dim3 ga(S / 128, H, B);  // (16, 16, 2)
  attn_fused<<<ga, 256, 0, stream>>>(B3, B0, B1, B2);  // ctx -> B2

  gemm_bt<0><<<gg, 128, 0, stream>>>(B2, Wob, bo, d_out, M, D, D);
}

// Round 2
// 165.746 us; speedup vs baseline: 1.1593x; 1.1593x over previous
//
#include <hip/hip_runtime.h>
#include <hip/hip_bf16.h>

typedef unsigned short u16;
typedef unsigned int u32;
typedef short s16x8 __attribute__((ext_vector_type(8)));
typedef float f32x4 __attribute__((ext_vector_type(4)));
typedef u32 u32x4 __attribute__((ext_vector_type(4)));

#define DEV static __device__ __forceinline__

DEV u16 bf16_rne(float f) {
  u32 u = __builtin_bit_cast(u32, f);
  u += 0x7fffu + ((u >> 16) & 1u);
  return (u16)(u >> 16);
}

DEV u32 pack2_bf16(float a, float b) {  // a -> low16, b -> high16 (both RNE)
  u32 ua = __builtin_bit_cast(u32, a);
  u32 ub = __builtin_bit_cast(u32, b);
  ua += 0x7fffu + ((ua >> 16) & 1u);
  ub += 0x7fffu + ((ub >> 16) & 1u);
  return (ua >> 16) | (ub & 0xffff0000u);
}

#define GLDS16(g, l)                                                           \
  __builtin_amdgcn_global_load_lds(                                           \
      (const __attribute__((address_space(1))) void*)(g),                     \
      (__attribute__((address_space(3))) void*)(l), 16, 0, 0)

// ---------------- convert fp32 -> bf16, up to 4 tensors per launch ----------
__global__ void cvt4_kernel(const float* s0, const float* s1, const float* s2,
                            const float* s3, u16* d0, u16* d1, u16* d2,
                            u16* d3, int n4) {
  const int z = blockIdx.y;
  const float* s = (z == 0) ? s0 : (z == 1) ? s1 : (z == 2) ? s2 : s3;
  u16* d = (z == 0) ? d0 : (z == 1) ? d1 : (z == 2) ? d2 : d3;
  int i = blockIdx.x * blockDim.x + threadIdx.x;
  if (i < n4) {
    float4 v = reinterpret_cast<const float4*>(s)[i];
    ushort4 o;
    o.x = bf16_rne(v.x);
    o.y = bf16_rne(v.y);
    o.z = bf16_rne(v.z);
    o.w = bf16_rne(v.w);
    reinterpret_cast<ushort4*>(d)[i] = o;
  }
}

// ---------------- GEMM: C[M,N] = A[M,K] * W[N,K]^T + bias ----------------
// BM=128, BN=128, BK=64. 256 threads = 4 waves (2x2), each wave 64x64.
// blockIdx.z selects the (A, W, bias, C) group (grouped QKV projection).
template <int OUT_BF16>
__global__ __launch_bounds__(256, 3) void gemm128(
    const u16* __restrict__ A0, const u16* __restrict__ A1,
    const u16* __restrict__ A2, const u16* __restrict__ W0,
    const u16* __restrict__ W1, const u16* __restrict__ W2,
    const float* __restrict__ bias0, const float* __restrict__ bias1,
    const float* __restrict__ bias2, void* __restrict__ C0,
    void* __restrict__ C1, void* __restrict__ C2, int M, int N, int K) {
  const int z = blockIdx.z;
  const u16* A = (z == 0) ? A0 : (z == 1) ? A1 : A2;
  const u16* W = (z == 0) ? W0 : (z == 1) ? W1 : W2;
  const float* bias = (z == 0) ? bias0 : (z == 1) ? bias1 : bias2;
  void* Cout = (z == 0) ? C0 : (z == 1) ? C1 : C2;

  __shared__ __align__(16) u16 As[128 * 64];
  __shared__ __align__(16) u16 Ws[128 * 64];
  const int tid = threadIdx.x;
  const int lane = tid & 63;
  const int w = tid >> 6;
  const int wr = w >> 1, wc = w & 1;
  const int l15 = lane & 15, l4 = lane >> 4;
  const int m0 = blockIdx.y * 128, n0 = blockIdx.x * 128;

  f32x4 acc[4][4] = {};
  float bv[4];
#pragma unroll
  for (int fc = 0; fc < 4; ++fc) bv[fc] = bias[n0 + wc * 64 + fc * 16 + l15];

  for (int kt = 0; kt < K; kt += 64) {
    __syncthreads();  // protect previous iteration's LDS reads
#pragma unroll
    for (int i = 0; i < 4; ++i) {  // A tile: 128 rows x 8 chunks = 1024
      const int ch = i * 256 + tid;
      const int row = ch >> 3, k8 = ch & 7;
      GLDS16(A + (size_t)(m0 + row) * K + kt + k8 * 8,
             As + (size_t)(i * 256 + w * 64) * 8);
    }
#pragma unroll
    for (int i = 0; i < 4; ++i) {  // W tile: 128 rows x 8 chunks
      const int ch = i * 256 + tid;
      const int row = ch >> 3, k8 = ch & 7;
      GLDS16(W + (size_t)(n0 + row) * K + kt + k8 * 8,
             Ws + (size_t)(i * 256 + w * 64) * 8);
    }
    __syncthreads();
#pragma unroll
    for (int ks = 0; ks < 2; ++ks) {
      s16x8 a[4], b[4];
#pragma unroll
      for (int f = 0; f < 4; ++f)
        a[f] = *(const s16x8*)(As + (wr * 64 + f * 16 + l15) * 64 + ks * 32 +
                               l4 * 8);
#pragma unroll
      for (int f = 0; f < 4; ++f)
        b[f] = *(const s16x8*)(Ws + (wc * 64 + f * 16 + l15) * 64 + ks * 32 +
                               l4 * 8);
#pragma unroll
      for (int fr = 0; fr < 4; ++fr)
#pragma unroll
        for (int fc = 0; fc < 4; ++fc)
          acc[fr][fc] = __builtin_amdgcn_mfma_f32_16x16x32_bf16(
              a[fr], b[fc], acc[fr][fc], 0, 0, 0);
    }
  }

#pragma unroll
  for (int fr = 0; fr < 4; ++fr) {
    const int mrow = m0 + wr * 64 + fr * 16 + l4 * 4;
#pragma unroll
    for (int fc = 0; fc < 4; ++fc) {
      const int ncol = n0 + wc * 64 + fc * 16 + l15;
#pragma unroll
      for (int r = 0; r < 4; ++r) {
        const float v = acc[fr][fc][r] + bv[fc];
        if (OUT_BF16)
          ((u16*)Cout)[(size_t)(mrow + r) * N + ncol] = bf16_rne(v);
        else
          ((float*)Cout)[(size_t)(mrow + r) * N + ncol] = v;
      }
    }
  }
}

// ---------------- fused flash attention ----------------
// grid (B*H, S/128), 512 threads = 8 waves; wave w owns q-cols [w*16, w*16+16).
// grid.x fastest => all q-tiles of one (b,h) land on the same XCD (lin%8 = bh%8)
// S^T = mfma(K, Q): q lane-local; P in registers -> shuffled to B-frag; PV via
// ctx^T = mfma(V^T, P). Reg-prefetch double-buffers K/V staging.
__global__ __launch_bounds__(512, 4) void attn_fused(
    const u16* __restrict__ qp, const u16* __restrict__ kp,
    const u16* __restrict__ vp, u16* __restrict__ ctx) {
  const int S = 2048, D = 1024;
  const int bh = blockIdx.x;
  const int h = bh & 15, b = bh >> 4;
  const int qt = blockIdx.y;
  const int tid = threadIdx.x, lane = tid & 63, w = tid >> 6;
  const int l15 = lane & 15, l4 = lane >> 4;

  // K tile [128 kv][64 d], 16B chunks swizzled: chunk col = d8 ^ (kv&7)
  __shared__ __align__(16) u16 Ks[128 * 64];
  // V^T tile [64 d][128 kv], chunk col = (kv>>3) ^ (d&7) ^ (d>>3)
  __shared__ __align__(16) u16 Vt[64 * 128];

  const size_t base = ((size_t)b * S) * D + (size_t)h * 64;

  s16x8 qf[2];
  {
    const int q = qt * 128 + w * 16 + l15;
    qf[0] = *(const s16x8*)(qp + base + (size_t)q * D + l4 * 8);
    qf[1] = *(const s16x8*)(qp + base + (size_t)q * D + 32 + l4 * 8);
  }

  f32x4 octx[4] = {};
  float m_run = -1e30f, l_run = 0.f;
  const float C1 = 0.125f * 1.44269504088896f;  // 1/sqrt(64) * log2(e)

  s16x8 pk_[2], pv_[2];  // prefetch registers
  const int srow = tid >> 3, sd8 = tid & 7;

  auto loadKV = [&](int t) {
    const size_t rb = base + (size_t)t * 128 * D;
#pragma unroll
    for (int i = 0; i < 2; ++i) {
      const int kvr = i * 64 + srow;
      pk_[i] = *(const s16x8*)(kp + rb + (size_t)kvr * D + sd8 * 8);
      pv_[i] = *(const s16x8*)(vp + rb + (size_t)kvr * D + sd8 * 8);
    }
  };
  auto writeKV = [&]() {
#pragma unroll
    for (int i = 0; i < 2; ++i) {
      const int kvr = i * 64 + srow;
      *(s16x8*)((char*)Ks + kvr * 128 + ((sd8 ^ (kvr & 7)) * 16)) = pk_[i];
      const int kv8 = kvr >> 3, kv7 = kvr & 7;
#pragma unroll
      for (int j = 0; j < 8; ++j) {
        const int d = sd8 * 8 + j;
        *(u16*)((char*)Vt + d * 256 + ((kv8 ^ (d & 7) ^ (d >> 3)) * 16) +
                kv7 * 2) = (u16)pv_[i][j];
      }
    }
  };

  loadKV(0);
  writeKV();

  for (int t = 0; t < S / 128; ++t) {
    __syncthreads();  // staged tile t visible
    if (t + 1 < S / 128) loadKV(t + 1);  // issue next-tile loads early (T14)

    // ---- scores^T: sc[fk], row=kv, col=q ----
    f32x4 sc[8] = {};
#pragma unroll
    for (int ks = 0; ks < 2; ++ks) {
      s16x8 kfr[8];
#pragma unroll
      for (int fk = 0; fk < 8; ++fk) {
        const int kv = fk * 16 + l15;
        const int d8 = ks * 4 + l4;
        kfr[fk] =
            *(const s16x8*)((char*)Ks + kv * 128 + ((d8 ^ (kv & 7)) * 16));
      }
      __builtin_amdgcn_s_setprio(1);
#pragma unroll
      for (int fk = 0; fk < 8; ++fk)
        sc[fk] = __builtin_amdgcn_mfma_f32_16x16x32_bf16(kfr[fk], qf[ks],
                                                         sc[fk], 0, 0, 0);
      __builtin_amdgcn_s_setprio(0);
    }

    // ---- online softmax (log2 domain) with defer-max (T13) ----
    float mt = sc[0][0];
#pragma unroll
    for (int fk = 0; fk < 8; ++fk)
      mt = fmaxf(mt, fmaxf(fmaxf(sc[fk][0], sc[fk][1]),
                           fmaxf(sc[fk][2], sc[fk][3])));
    mt = fmaxf(mt, __shfl_xor(mt, 16, 64));
    mt = fmaxf(mt, __shfl_xor(mt, 32, 64));
    mt *= C1;
    if (!__all(mt - m_run <= 11.5f)) {
      const float mnew = fmaxf(m_run, mt);
      const float resc = __builtin_amdgcn_exp2f(m_run - mnew);
      m_run = mnew;
      l_run *= resc;
#pragma unroll
      for (int fd = 0; fd < 4; ++fd)
#pragma unroll
        for (int r = 0; r < 4; ++r) octx[fd][r] *= resc;
    }
    float rsum = 0.f;
    u32 pkA[8], pkB[8];
#pragma unroll
    for (int fk = 0; fk < 8; ++fk) {
      const float p0 = __builtin_amdgcn_exp2f(fmaf(sc[fk][0], C1, -m_run));
      const float p1 = __builtin_amdgcn_exp2f(fmaf(sc[fk][1], C1, -m_run));
      const float p2 = __builtin_amdgcn_exp2f(fmaf(sc[fk][2], C1, -m_run));
      const float p3 = __builtin_amdgcn_exp2f(fmaf(sc[fk][3], C1, -m_run));
      rsum += (p0 + p1) + (p2 + p3);
      pkA[fk] = pack2_bf16(p0, p1);
      pkB[fk] = pack2_bf16(p2, p3);
    }
    rsum += __shfl_xor(rsum, 16, 64);
    rsum += __shfl_xor(rsum, 32, 64);
    l_run += rsum;

    // ---- PV: octx[fd] += mfma(V^T frag, P B-frag) ----
#pragma unroll
    for (int c = 0; c < 4; ++c) {  // kv 32-chunk
      u32x4 wvv;
#pragma unroll
      for (int jj = 0; jj < 4; ++jj) {
        const int src = ((l4 & 1) * 2 + (jj >> 1)) * 16 + l15;
        const u32 c0 = (jj & 1) ? pkB[2 * c] : pkA[2 * c];
        const u32 c1 = (jj & 1) ? pkB[2 * c + 1] : pkA[2 * c + 1];
        const u32 v0 = (u32)__shfl((int)c0, src, 64);
        const u32 v1 = (u32)__shfl((int)c1, src, 64);
        wvv[jj] = (l4 < 2) ? v0 : v1;
      }
      const s16x8 pb = __builtin_bit_cast(s16x8, wvv);
      __builtin_amdgcn_s_setprio(1);
#pragma unroll
      for (int fd = 0; fd < 4; ++fd) {
        const int d = fd * 16 + l15;
        const s16x8 vf = *(const s16x8*)(
            (const char*)Vt + d * 256 +
            (((c * 4 + l4) ^ (d & 7) ^ (d >> 3)) * 16));
        octx[fd] =
            __builtin_amdgcn_mfma_f32_16x16x32_bf16(vf, pb, octx[fd], 0, 0, 0);
      }
      __builtin_amdgcn_s_setprio(0);
    }

    __syncthreads();  // all waves done reading tile t
    if (t + 1 < S / 128) writeKV();  // vmcnt wait lands here, hidden by compute
  }

  // ---- finalize: ctx[q][h*64+d] = octx^T / l ----
  {
    const float inv = 1.f / l_run;
    const int q = qt * 128 + w * 16 + l15;
#pragma unroll
    for (int fd = 0; fd < 4; ++fd) {
      ushort4 o;
      o.x = bf16_rne(octx[fd][0] * inv);
      o.y = bf16_rne(octx[fd][1] * inv);
      o.z = bf16_rne(octx[fd][2] * inv);
      o.w = bf16_rne(octx[fd][3] * inv);
      *reinterpret_cast<ushort4*>(ctx + base + (size_t)q * D + fd * 16 +
                                  l4 * 4) = o;
    }
  }
}

// ---------------- launcher ----------------
extern "C" void kernel_launch(void* const* d_in, const int* in_sizes, int n_in,
                              void* d_out, int out_size, void* d_ws,
                              size_t ws_size, hipStream_t stream) {
  (void)in_sizes; (void)n_in; (void)out_size;
  const float* Q = (const float*)d_in[0];
  const float* K = (const float*)d_in[1];
  const float* V = (const float*)d_in[2];
  const float* Wq = (const float*)d_in[3];
  const float* bq = (const float*)d_in[4];
  const float* Wk = (const float*)d_in[5];
  const float* bk = (const float*)d_in[6];
  const float* Wv = (const float*)d_in[7];
  const float* bv = (const float*)d_in[8];
  const float* Wo = (const float*)d_in[9];
  const float* bo = (const float*)d_in[10];

  const int B = 2, S = 2048, D = 1024, H = 16;
  const int M = B * S;              // 4096
  const size_t NE = (size_t)M * D;  // 4M elems
  const size_t WE = (size_t)D * D;  // 1M elems

  const int n4 = (int)(NE / 4), nb = (n4 + 255) / 256;
  const int w4 = (int)(WE / 4), wb = (w4 + 255) / 256;
  dim3 gg(D / 128, M / 128, 3);  // (8, 32, 3) grouped QKV
  dim3 go(D / 128, M / 128, 1);
  dim3 ga(B * H, S / 128);  // (32, 16): lin%8 = bh%8 -> per-head XCD affinity

  const bool big = ws_size >= (size_t)(6 * NE + 4 * WE) * 2;

  if (big) {
    u16* B0 = (u16*)d_ws;  // Qb, later ctx
    u16* B1 = B0 + NE;     // Kb
    u16* B2 = B1 + NE;     // Vb
    u16* B3 = B2 + NE;     // qp
    u16* B4 = B3 + NE;     // kp
    u16* B5 = B4 + NE;     // vp
    u16* Wqb = B5 + NE;
    u16* Wkb = Wqb + WE;
    u16* Wvb = Wkb + WE;
    u16* Wob = Wvb + WE;

    cvt4_kernel<<<dim3(nb, 3), 256, 0, stream>>>(Q, K, V, nullptr, B0, B1, B2,
                                                 nullptr, n4);
    cvt4_kernel<<<dim3(wb, 4), 256, 0, stream>>>(Wq, Wk, Wv, Wo, Wqb, Wkb, Wvb,
                                                 Wob, w4);
    gemm128<1><<<gg, 256, 0, stream>>>(B0, B1, B2, Wqb, Wkb, Wvb, bq, bk, bv,
                                       B3, B4, B5, M, D, D);
    attn_fused<<<ga, 512, 0, stream>>>(B3, B4, B5, B0);
    gemm128<0><<<go, 256, 0, stream>>>(B0, B0, B0, Wob, Wob, Wob, bo, bo, bo,
                                       d_out, d_out, d_out, M, D, D);
  } else {
    // fallback: sequential projections, 40 MB workspace (round-0 layout)
    u16* B0 = (u16*)d_ws;  // Qb -> kp
    u16* B1 = B0 + NE;     // Kb -> vp
    u16* B2 = B1 + NE;     // Vb -> ctx
    u16* B3 = B2 + NE;     // qp
    u16* Wqb = B3 + NE;
    u16* Wkb = Wqb + WE;
    u16* Wvb = Wkb + WE;
    u16* Wob = Wvb + WE;

    cvt4_kernel<<<dim3(nb, 3), 256, 0, stream>>>(Q, K, V, nullptr, B0, B1, B2,
                                                 nullptr, n4);
    cvt4_kernel<<<dim3(wb, 4), 256, 0, stream>>>(Wq, Wk, Wv, Wo, Wqb, Wkb, Wvb,
                                                 Wob, w4);
    gemm128<1><<<go, 256, 0, stream>>>(B0, B0, B0, Wqb, Wqb, Wqb, bq, bq, bq,
                                       B3, B3, B3, M, D, D);
    gemm128<1><<<go, 256, 0, stream>>>(B1, B1, B1, Wkb, Wkb, Wkb, bk, bk, bk,
                                       B0, B0, B0, M, D, D);
    gemm128<1><<<go, 256, 0, stream>>>(B2, B2, B2, Wvb, Wvb, Wvb, bv, bv, bv,
                                       B1, B1, B1, M, D, D);
    attn_fused<<<ga, 512, 0, stream>>>(B3, B0, B1, B2);
    gemm128<0><<<go, 256, 0, stream>>>(B2, B2, B2, Wob, Wob, Wob, bo, bo, bo,
                                       d_out, d_out, d_out, M, D, D);
  }
}

// Round 3
// 133.186 us; speedup vs baseline: 1.4427x; 1.2445x over previous
//
#include <hip/hip_runtime.h>
#include <hip/hip_bf16.h>

typedef unsigned short u16;
typedef unsigned int u32;
typedef short s16x8 __attribute__((ext_vector_type(8)));
typedef float f32x4 __attribute__((ext_vector_type(4)));
typedef float f32x16 __attribute__((ext_vector_type(16)));
typedef u32 u32x4 __attribute__((ext_vector_type(4)));

#define DEV static __device__ __forceinline__

DEV u16 bf16_rne(float f) {
  u32 u = __builtin_bit_cast(u32, f);
  u += 0x7fffu + ((u >> 16) & 1u);
  return (u16)(u >> 16);
}

#define GLDS16(g, l)                                                           \
  __builtin_amdgcn_global_load_lds(                                           \
      (const __attribute__((address_space(1))) void*)(g),                     \
      (__attribute__((address_space(3))) void*)(l), 16, 0, 0)

// ---------------- convert fp32 -> bf16, up to 4 tensors per launch ----------
__global__ void cvt4_kernel(const float* s0, const float* s1, const float* s2,
                            const float* s3, u16* d0, u16* d1, u16* d2,
                            u16* d3, int n4) {
  const int z = blockIdx.y;
  const float* s = (z == 0) ? s0 : (z == 1) ? s1 : (z == 2) ? s2 : s3;
  u16* d = (z == 0) ? d0 : (z == 1) ? d1 : (z == 2) ? d2 : d3;
  int i = blockIdx.x * blockDim.x + threadIdx.x;
  if (i < n4) {
    float4 v = reinterpret_cast<const float4*>(s)[i];
    ushort4 o;
    o.x = bf16_rne(v.x);
    o.y = bf16_rne(v.y);
    o.z = bf16_rne(v.z);
    o.w = bf16_rne(v.w);
    reinterpret_cast<ushort4*>(d)[i] = o;
  }
}

// ---------------- GEMM: C[M,N] = A[M,K] * W[N,K]^T + bias ----------------
// BM=128, BN=128, BK=64. 256 threads = 4 waves (2x2), each wave 64x64.
// blockIdx.z selects the (A, W, bias, C) group (grouped QKV projection).
// VT: 0 = never transpose output, 1 = z==2 writes vt[b][h][d][s], 2 = always vt.
template <int OUT_BF16, int VT>
__global__ __launch_bounds__(256, 3) void gemm128(
    const u16* __restrict__ A0, const u16* __restrict__ A1,
    const u16* __restrict__ A2, const u16* __restrict__ W0,
    const u16* __restrict__ W1, const u16* __restrict__ W2,
    const float* __restrict__ bias0, const float* __restrict__ bias1,
    const float* __restrict__ bias2, void* __restrict__ C0,
    void* __restrict__ C1, void* __restrict__ C2, int M, int N, int K) {
  const int z = blockIdx.z;
  const u16* A = (z == 0) ? A0 : (z == 1) ? A1 : A2;
  const u16* W = (z == 0) ? W0 : (z == 1) ? W1 : W2;
  const float* bias = (z == 0) ? bias0 : (z == 1) ? bias1 : bias2;
  void* Cout = (z == 0) ? C0 : (z == 1) ? C1 : C2;

  __shared__ __align__(16) u16 As[128 * 64];
  __shared__ __align__(16) u16 Ws[128 * 64];
  const int tid = threadIdx.x;
  const int lane = tid & 63;
  const int w = tid >> 6;
  const int wr = w >> 1, wc = w & 1;
  const int l15 = lane & 15, l4 = lane >> 4;
  const int m0 = blockIdx.y * 128, n0 = blockIdx.x * 128;

  f32x4 acc[4][4] = {};
  float bv[4];
#pragma unroll
  for (int fc = 0; fc < 4; ++fc) bv[fc] = bias[n0 + wc * 64 + fc * 16 + l15];

  for (int kt = 0; kt < K; kt += 64) {
    __syncthreads();  // protect previous iteration's LDS reads
#pragma unroll
    for (int i = 0; i < 4; ++i) {  // A tile: 128 rows x 8 chunks = 1024
      const int ch = i * 256 + tid;
      const int row = ch >> 3, k8 = ch & 7;
      GLDS16(A + (size_t)(m0 + row) * K + kt + k8 * 8,
             As + (size_t)(i * 256 + w * 64) * 8);
    }
#pragma unroll
    for (int i = 0; i < 4; ++i) {  // W tile: 128 rows x 8 chunks
      const int ch = i * 256 + tid;
      const int row = ch >> 3, k8 = ch & 7;
      GLDS16(W + (size_t)(n0 + row) * K + kt + k8 * 8,
             Ws + (size_t)(i * 256 + w * 64) * 8);
    }
    __syncthreads();
#pragma unroll
    for (int ks = 0; ks < 2; ++ks) {
      s16x8 a[4], b[4];
#pragma unroll
      for (int f = 0; f < 4; ++f)
        a[f] = *(const s16x8*)(As + (wr * 64 + f * 16 + l15) * 64 + ks * 32 +
                               l4 * 8);
#pragma unroll
      for (int f = 0; f < 4; ++f)
        b[f] = *(const s16x8*)(Ws + (wc * 64 + f * 16 + l15) * 64 + ks * 32 +
                               l4 * 8);
#pragma unroll
      for (int fr = 0; fr < 4; ++fr)
#pragma unroll
        for (int fc = 0; fc < 4; ++fc)
          acc[fr][fc] = __builtin_amdgcn_mfma_f32_16x16x32_bf16(
              a[fr], b[fc], acc[fr][fc], 0, 0, 0);
    }
  }

  const bool do_vt = (VT == 2) || (VT == 1 && z == 2);
  if (do_vt) {
    // vt[b][h][d][s]: b = m>>11, s = m&2047, h = n>>6, d = n&63
#pragma unroll
    for (int fr = 0; fr < 4; ++fr) {
      const int m = m0 + wr * 64 + fr * 16 + l4 * 4;
      const int bb = m >> 11, s = m & 2047;
#pragma unroll
      for (int fc = 0; fc < 4; ++fc) {
        const int n = n0 + wc * 64 + fc * 16 + l15;
        const int hh = n >> 6, dd = n & 63;
        ushort4 o;
        o.x = bf16_rne(acc[fr][fc][0] + bv[fc]);
        o.y = bf16_rne(acc[fr][fc][1] + bv[fc]);
        o.z = bf16_rne(acc[fr][fc][2] + bv[fc]);
        o.w = bf16_rne(acc[fr][fc][3] + bv[fc]);
        *(ushort4*)((u16*)Cout +
                    (((size_t)(bb * 16 + hh) * 64 + dd) * 2048 + s)) = o;
      }
    }
  } else {
#pragma unroll
    for (int fr = 0; fr < 4; ++fr) {
      const int mrow = m0 + wr * 64 + fr * 16 + l4 * 4;
#pragma unroll
      for (int fc = 0; fc < 4; ++fc) {
        const int ncol = n0 + wc * 64 + fc * 16 + l15;
#pragma unroll
        for (int r = 0; r < 4; ++r) {
          const float v = acc[fr][fc][r] + bv[fc];
          if (OUT_BF16)
            ((u16*)Cout)[(size_t)(mrow + r) * N + ncol] = bf16_rne(v);
          else
            ((float*)Cout)[(size_t)(mrow + r) * N + ncol] = v;
        }
      }
    }
  }
}

// ---------------- fused flash attention (32x32 MFMA + permlane P-path) -----
// grid (B*H, S/128), 256 threads = 4 waves; wave w owns q-cols [w*32, +32).
// S^T = mfma32(K, Q): q lane-local (l31). P stays in registers: cvt_pk to
// bf16 + v_permlane32_swap builds PV B-frags (T12). K and V^T staged via
// global_load_lds (pre-swizzled sources), double-buffered, 1 barrier/tile.
__global__ __launch_bounds__(256, 2) void attn_fused(
    const u16* __restrict__ qp, const u16* __restrict__ kp,
    const u16* __restrict__ vt, u16* __restrict__ ctx) {
  const int S = 2048, D = 1024;
  const int bh = blockIdx.x;  // b*16 + h ; bh%8 = XCD affinity per head
  const int qt = blockIdx.y;
  const int tid = threadIdx.x, lane = tid & 63, w = tid >> 6;
  const int l31 = lane & 31, l5 = lane >> 5;

  // K: [128 kv][8 x 16B chunks], chunk col = c ^ (kv&7)
  // V^T: [64 d][16 x 16B chunks], chunk col = c ^ (d&7)
  __shared__ __align__(16) u16 KsL[2][128 * 64];
  __shared__ __align__(16) u16 VtL[2][64 * 128];

  const size_t qkbase =
      ((size_t)(bh >> 4) * S) * D + (size_t)(bh & 15) * 64;
  const size_t vbase = (size_t)bh * 64 * S;  // vt[bh][d][s]

  // Q B-frags: n = q = l31, k = l5*8 + j, per ks (d 16-chunk)
  const int q = qt * 128 + w * 32 + l31;
  s16x8 qf[4];
#pragma unroll
  for (int ks = 0; ks < 4; ++ks)
    qf[ks] = *(const s16x8*)(qp + qkbase + (size_t)q * D + ks * 16 + l5 * 8);

  f32x16 octx[2] = {};
  float m_run = -1e30f, l_run = 0.f;
  const float C1 = 0.125f * 1.44269504088896f;  // 1/sqrt(64) * log2(e)

  auto stage = [&](int buf, int t) {
    const int kv0 = t * 128;
#pragma unroll
    for (int i = 0; i < 4; ++i) {  // K tile: 1024 chunks
      const int g = i * 256 + tid;
      const int kv = g >> 3, cc = g & 7;
      GLDS16(kp + qkbase + (size_t)(kv0 + kv) * D + ((cc ^ (kv & 7)) << 3),
             &KsL[buf][(size_t)(i * 256 + w * 64) * 8]);
    }
#pragma unroll
    for (int i = 0; i < 4; ++i) {  // V^T tile: 1024 chunks
      const int g = i * 256 + tid;
      const int d = g >> 4, cc = g & 15;
      GLDS16(vt + vbase + (size_t)d * S + kv0 + ((cc ^ (d & 7)) << 3),
             &VtL[buf][(size_t)(i * 256 + w * 64) * 8]);
    }
  };

  stage(0, 0);
  const int NT = S / 128;  // 16
  for (int t = 0; t < NT; ++t) {
    __syncthreads();  // drains tile-t loads (vmcnt0) + orders buffer reuse
    if (t + 1 < NT) stage((t + 1) & 1, t + 1);  // fly during compute of t
    const u16* Kb = KsL[t & 1];
    const u16* Vb = VtL[t & 1];

    // ---- scores^T: sc[fk] = K[fk*32..][*] x Q -> rows kv, cols q ----
    f32x16 sc[4] = {};
#pragma unroll
    for (int ks = 0; ks < 4; ++ks) {
      __builtin_amdgcn_s_setprio(1);
#pragma unroll
      for (int fk = 0; fk < 4; ++fk) {
        const int kv = fk * 32 + l31;
        const s16x8 kf = *(const s16x8*)(
            Kb + (size_t)(kv * 8 + (((ks << 1) + l5) ^ (kv & 7))) * 8);
        sc[fk] = __builtin_amdgcn_mfma_f32_32x32x16_bf16(kf, qf[ks], sc[fk],
                                                         0, 0, 0);
      }
      __builtin_amdgcn_s_setprio(0);
    }

    // ---- online softmax (log2 domain), defer-max (T13) ----
    float mt = sc[0][0];
#pragma unroll
    for (int fk = 0; fk < 4; ++fk)
#pragma unroll
      for (int r = 0; r < 16; ++r) mt = fmaxf(mt, sc[fk][r]);
    mt = fmaxf(mt, __shfl_xor(mt, 32, 64));
    mt *= C1;
    if (!__all(mt - m_run <= 11.5f)) {
      const float mnew = fmaxf(m_run, mt);
      const float resc = __builtin_amdgcn_exp2f(m_run - mnew);
      m_run = mnew;
      l_run *= resc;
#pragma unroll
      for (int fd = 0; fd < 2; ++fd)
#pragma unroll
        for (int r = 0; r < 16; ++r) octx[fd][r] *= resc;
    }
    float rsum = 0.f;
#pragma unroll
    for (int fk = 0; fk < 4; ++fk)
#pragma unroll
      for (int r = 0; r < 16; ++r) {
        const float p = __builtin_amdgcn_exp2f(fmaf(sc[fk][r], C1, -m_run));
        sc[fk][r] = p;
        rsum += p;
      }
    rsum += __shfl_xor(rsum, 32, 64);
    l_run += rsum;

    // ---- PV: octx[fd] += mfma32(V^T frag, P B-frag) ----
    // P B-frag per 16-kv chunk: 4 cvt_pk + 2 permlane32_swap (T12).
#pragma unroll
    for (int fk = 0; fk < 4; ++fk) {
#pragma unroll
      for (int hf = 0; hf < 2; ++hf) {
        u32 x0, x1, y0, y1;
        asm("v_cvt_pk_bf16_f32 %0, %1, %2"
            : "=v"(x0)
            : "v"(sc[fk][hf * 8 + 0]), "v"(sc[fk][hf * 8 + 1]));
        asm("v_cvt_pk_bf16_f32 %0, %1, %2"
            : "=v"(x1)
            : "v"(sc[fk][hf * 8 + 2]), "v"(sc[fk][hf * 8 + 3]));
        asm("v_cvt_pk_bf16_f32 %0, %1, %2"
            : "=v"(y0)
            : "v"(sc[fk][hf * 8 + 4]), "v"(sc[fk][hf * 8 + 5]));
        asm("v_cvt_pk_bf16_f32 %0, %1, %2"
            : "=v"(y1)
            : "v"(sc[fk][hf * 8 + 6]), "v"(sc[fk][hf * 8 + 7]));
        // after swap: x = [x.lo | y.lo] (words 0/1), y = [x.hi | y.hi] (2/3)
        asm("v_permlane32_swap_b32 %0, %1" : "+v"(x0), "+v"(y0));
        asm("v_permlane32_swap_b32 %0, %1" : "+v"(x1), "+v"(y1));
        u32x4 bw;
        bw[0] = x0; bw[1] = x1; bw[2] = y0; bw[3] = y1;
        const s16x8 pb = __builtin_bit_cast(s16x8, bw);
        const int tc = fk * 2 + hf;
        __builtin_amdgcn_s_setprio(1);
#pragma unroll
        for (int fd = 0; fd < 2; ++fd) {
          const int d = fd * 32 + l31;
          const s16x8 vf = *(const s16x8*)(
              Vb + (size_t)(d * 16 + (((tc << 1) + l5) ^ (d & 7))) * 8);
          octx[fd] = __builtin_amdgcn_mfma_f32_32x32x16_bf16(vf, pb, octx[fd],
                                                             0, 0, 0);
        }
        __builtin_amdgcn_s_setprio(0);
      }
    }
  }

  // ---- finalize: ctx[q][h*64+d] = octx^T / l ----
  const float inv = 1.f / l_run;
#pragma unroll
  for (int fd = 0; fd < 2; ++fd)
#pragma unroll
    for (int g = 0; g < 4; ++g) {
      // reg = g*4 + j -> d = fd*32 + g*8 + l5*4 + j
      ushort4 o;
      o.x = bf16_rne(octx[fd][g * 4 + 0] * inv);
      o.y = bf16_rne(octx[fd][g * 4 + 1] * inv);
      o.z = bf16_rne(octx[fd][g * 4 + 2] * inv);
      o.w = bf16_rne(octx[fd][g * 4 + 3] * inv);
      *(ushort4*)(ctx + qkbase + (size_t)q * D + fd * 32 + g * 8 + l5 * 4) = o;
    }
}

// ---------------- launcher ----------------
extern "C" void kernel_launch(void* const* d_in, const int* in_sizes, int n_in,
                              void* d_out, int out_size, void* d_ws,
                              size_t ws_size, hipStream_t stream) {
  (void)in_sizes; (void)n_in; (void)out_size;
  const float* Q = (const float*)d_in[0];
  const float* K = (const float*)d_in[1];
  const float* V = (const float*)d_in[2];
  const float* Wq = (const float*)d_in[3];
  const float* bq = (const float*)d_in[4];
  const float* Wk = (const float*)d_in[5];
  const float* bk = (const float*)d_in[6];
  const float* Wv = (const float*)d_in[7];
  const float* bv = (const float*)d_in[8];
  const float* Wo = (const float*)d_in[9];
  const float* bo = (const float*)d_in[10];

  const int B = 2, S = 2048, D = 1024, H = 16;
  const int M = B * S;              // 4096
  const size_t NE = (size_t)M * D;  // 4M elems
  const size_t WE = (size_t)D * D;  // 1M elems

  const int n4 = (int)(NE / 4), nb = (n4 + 255) / 256;
  const int w4 = (int)(WE / 4), wb = (w4 + 255) / 256;
  dim3 gg(D / 128, M / 128, 3);  // grouped QKV
  dim3 go(D / 128, M / 128, 1);
  dim3 ga(B * H, S / 128);  // (32, 16): bh fastest -> per-head XCD affinity

  const bool big = ws_size >= (size_t)(6 * NE + 4 * WE) * 2;

  if (big) {
    u16* B0 = (u16*)d_ws;  // Qb, later ctx
    u16* B1 = B0 + NE;     // Kb
    u16* B2 = B1 + NE;     // Vb
    u16* B3 = B2 + NE;     // qp
    u16* B4 = B3 + NE;     // kp
    u16* B5 = B4 + NE;     // vt  [b][h][d][s]
    u16* Wqb = B5 + NE;
    u16* Wkb = Wqb + WE;
    u16* Wvb = Wkb + WE;
    u16* Wob = Wvb + WE;

    cvt4_kernel<<<dim3(nb, 3), 256, 0, stream>>>(Q, K, V, nullptr, B0, B1, B2,
                                                 nullptr, n4);
    cvt4_kernel<<<dim3(wb, 4), 256, 0, stream>>>(Wq, Wk, Wv, Wo, Wqb, Wkb, Wvb,
                                                 Wob, w4);
    gemm128<1, 1><<<gg, 256, 0, stream>>>(B0, B1, B2, Wqb, Wkb, Wvb, bq, bk,
                                          bv, B3, B4, B5, M, D, D);
    attn_fused<<<ga, 256, 0, stream>>>(B3, B4, B5, B0);
    gemm128<0, 0><<<go, 256, 0, stream>>>(B0, B0, B0, Wob, Wob, Wob, bo, bo,
                                          bo, d_out, d_out, d_out, M, D, D);
  } else {
    // fallback: sequential projections, smaller workspace
    u16* B0 = (u16*)d_ws;  // Qb -> kp
    u16* B1 = B0 + NE;     // Kb -> vt
    u16* B2 = B1 + NE;     // Vb -> ctx
    u16* B3 = B2 + NE;     // qp
    u16* Wqb = B3 + NE;
    u16* Wkb = Wqb + WE;
    u16* Wvb = Wkb + WE;
    u16* Wob = Wvb + WE;

    cvt4_kernel<<<dim3(nb, 3), 256, 0, stream>>>(Q, K, V, nullptr, B0, B1, B2,
                                                 nullptr, n4);
    cvt4_kernel<<<dim3(wb, 4), 256, 0, stream>>>(Wq, Wk, Wv, Wo, Wqb, Wkb, Wvb,
                                                 Wob, w4);
    gemm128<1, 0><<<go, 256, 0, stream>>>(B0, B0, B0, Wqb, Wqb, Wqb, bq, bq,
                                          bq, B3, B3, B3, M, D, D);
    gemm128<1, 2><<<go, 256, 0, stream>>>(B2, B2, B2, Wvb, Wvb, Wvb, bv, bv,
                                          bv, B1, B1, B1, M, D, D);  // vt (uses Vb in B2 first)
    gemm128<1, 0><<<go, 256, 0, stream>>>(B0, B0, B0, Wkb, Wkb, Wkb, bk, bk,
                                          bk, B0, B0, B0, M, D, D);  // kp over Qb... keep order safe:
    attn_fused<<<ga, 256, 0, stream>>>(B3, B0, B1, B2);
    gemm128<0, 0><<<go, 256, 0, stream>>>(B2, B2, B2, Wob, Wob, Wob, bo, bo,
                                          bo, d_out, d_out, d_out, M, D, D);
  }
}

// Round 4
// 132.452 us; speedup vs baseline: 1.4507x; 1.0055x over previous
//
#include <hip/hip_runtime.h>
#include <hip/hip_bf16.h>

typedef unsigned short u16;
typedef unsigned int u32;
typedef short s16x8 __attribute__((ext_vector_type(8)));
typedef float f32x4 __attribute__((ext_vector_type(4)));
typedef float f32x16 __attribute__((ext_vector_type(16)));
typedef u32 u32x4 __attribute__((ext_vector_type(4)));

#define DEV static __device__ __forceinline__

DEV u16 bf16_rne(float f) {
  u32 u = __builtin_bit_cast(u32, f);
  u += 0x7fffu + ((u >> 16) & 1u);
  return (u16)(u >> 16);
}

#define GLDS16(g, l)                                                           \
  __builtin_amdgcn_global_load_lds(                                           \
      (const __attribute__((address_space(1))) void*)(g),                     \
      (__attribute__((address_space(3))) void*)(l), 16, 0, 0)

// ---------------- convert fp32 -> bf16, up to 4 tensors per launch ----------
__global__ void cvt4_kernel(const float* s0, const float* s1, const float* s2,
                            const float* s3, u16* d0, u16* d1, u16* d2,
                            u16* d3, int n4) {
  const int z = blockIdx.y;
  const float* s = (z == 0) ? s0 : (z == 1) ? s1 : (z == 2) ? s2 : s3;
  u16* d = (z == 0) ? d0 : (z == 1) ? d1 : (z == 2) ? d2 : d3;
  int i = blockIdx.x * blockDim.x + threadIdx.x;
  if (i < n4) {
    float4 v = reinterpret_cast<const float4*>(s)[i];
    ushort4 o;
    o.x = bf16_rne(v.x);
    o.y = bf16_rne(v.y);
    o.z = bf16_rne(v.z);
    o.w = bf16_rne(v.w);
    reinterpret_cast<ushort4*>(d)[i] = o;
  }
}

// ---------------- GEMM: C[M,N] = A[M,K] * W[N,K]^T + bias ----------------
// BM=128, BN=128, BK=64. 256 threads = 4 waves (2x2), each wave 64x64.
// blockIdx.z selects the (A, W, bias, C) group (grouped QKV projection).
// VT: 0 = never transpose output, 1 = z==2 writes vt[b][h][d][s], 2 = always vt.
template <int OUT_BF16, int VT>
__global__ __launch_bounds__(256, 3) void gemm128(
    const u16* __restrict__ A0, const u16* __restrict__ A1,
    const u16* __restrict__ A2, const u16* __restrict__ W0,
    const u16* __restrict__ W1, const u16* __restrict__ W2,
    const float* __restrict__ bias0, const float* __restrict__ bias1,
    const float* __restrict__ bias2, void* __restrict__ C0,
    void* __restrict__ C1, void* __restrict__ C2, int M, int N, int K) {
  const int z = blockIdx.z;
  const u16* A = (z == 0) ? A0 : (z == 1) ? A1 : A2;
  const u16* W = (z == 0) ? W0 : (z == 1) ? W1 : W2;
  const float* bias = (z == 0) ? bias0 : (z == 1) ? bias1 : bias2;
  void* Cout = (z == 0) ? C0 : (z == 1) ? C1 : C2;

  __shared__ __align__(16) u16 As[128 * 64];
  __shared__ __align__(16) u16 Ws[128 * 64];
  const int tid = threadIdx.x;
  const int lane = tid & 63;
  const int w = tid >> 6;
  const int wr = w >> 1, wc = w & 1;
  const int l15 = lane & 15, l4 = lane >> 4;
  const int m0 = blockIdx.y * 128, n0 = blockIdx.x * 128;

  f32x4 acc[4][4] = {};
  float bv[4];
#pragma unroll
  for (int fc = 0; fc < 4; ++fc) bv[fc] = bias[n0 + wc * 64 + fc * 16 + l15];

  for (int kt = 0; kt < K; kt += 64) {
    __syncthreads();  // protect previous iteration's LDS reads
#pragma unroll
    for (int i = 0; i < 4; ++i) {  // A tile: 128 rows x 8 chunks = 1024
      const int ch = i * 256 + tid;
      const int row = ch >> 3, k8 = ch & 7;
      GLDS16(A + (size_t)(m0 + row) * K + kt + k8 * 8,
             As + (size_t)(i * 256 + w * 64) * 8);
    }
#pragma unroll
    for (int i = 0; i < 4; ++i) {  // W tile: 128 rows x 8 chunks
      const int ch = i * 256 + tid;
      const int row = ch >> 3, k8 = ch & 7;
      GLDS16(W + (size_t)(n0 + row) * K + kt + k8 * 8,
             Ws + (size_t)(i * 256 + w * 64) * 8);
    }
    __syncthreads();
#pragma unroll
    for (int ks = 0; ks < 2; ++ks) {
      s16x8 a[4], b[4];
#pragma unroll
      for (int f = 0; f < 4; ++f)
        a[f] = *(const s16x8*)(As + (wr * 64 + f * 16 + l15) * 64 + ks * 32 +
                               l4 * 8);
#pragma unroll
      for (int f = 0; f < 4; ++f)
        b[f] = *(const s16x8*)(Ws + (wc * 64 + f * 16 + l15) * 64 + ks * 32 +
                               l4 * 8);
#pragma unroll
      for (int fr = 0; fr < 4; ++fr)
#pragma unroll
        for (int fc = 0; fc < 4; ++fc)
          acc[fr][fc] = __builtin_amdgcn_mfma_f32_16x16x32_bf16(
              a[fr], b[fc], acc[fr][fc], 0, 0, 0);
    }
  }

  const bool do_vt = (VT == 2) || (VT == 1 && z == 2);
  if (do_vt) {
    // vt[b][h][d][s]: b = m>>11, s = m&2047, h = n>>6, d = n&63
#pragma unroll
    for (int fr = 0; fr < 4; ++fr) {
      const int m = m0 + wr * 64 + fr * 16 + l4 * 4;
      const int bb = m >> 11, s = m & 2047;
#pragma unroll
      for (int fc = 0; fc < 4; ++fc) {
        const int n = n0 + wc * 64 + fc * 16 + l15;
        const int hh = n >> 6, dd = n & 63;
        ushort4 o;
        o.x = bf16_rne(acc[fr][fc][0] + bv[fc]);
        o.y = bf16_rne(acc[fr][fc][1] + bv[fc]);
        o.z = bf16_rne(acc[fr][fc][2] + bv[fc]);
        o.w = bf16_rne(acc[fr][fc][3] + bv[fc]);
        *(ushort4*)((u16*)Cout +
                    (((size_t)(bb * 16 + hh) * 64 + dd) * 2048 + s)) = o;
      }
    }
  } else {
#pragma unroll
    for (int fr = 0; fr < 4; ++fr) {
      const int mrow = m0 + wr * 64 + fr * 16 + l4 * 4;
#pragma unroll
      for (int fc = 0; fc < 4; ++fc) {
        const int ncol = n0 + wc * 64 + fc * 16 + l15;
#pragma unroll
        for (int r = 0; r < 4; ++r) {
          const float v = acc[fr][fc][r] + bv[fc];
          if (OUT_BF16)
            ((u16*)Cout)[(size_t)(mrow + r) * N + ncol] = bf16_rne(v);
          else
            ((float*)Cout)[(size_t)(mrow + r) * N + ncol] = v;
        }
      }
    }
  }
}

// ---------------- fused flash attention: 2-way kv-split, 32x32 MFMA --------
// grid (B*H, S/128), 512 threads = 8 waves: wave w = q-chunk (w&3, 32 q each)
// x kv-group (w>>2; group g covers kv in [g*1024, g*1024+1024), 16 tiles of 64).
// Per group: K [2][64][64] + V^T [2][64][64] double-buffered (32 KB/group).
// End: flash-combine the two groups' (m,l,O) via LDS scratch.
__global__ __launch_bounds__(512, 4) void attn_fused(
    const u16* __restrict__ qp, const u16* __restrict__ kp,
    const u16* __restrict__ vt, u16* __restrict__ ctx) {
  const int S = 2048, D = 1024;
  const int bh = blockIdx.x;  // b*16 + h ; bh%8 = XCD affinity per head
  const int qt = blockIdx.y;
  const int tid = threadIdx.x, lane = tid & 63, w = tid >> 6;
  const int l31 = lane & 31, l5 = lane >> 5;
  const int g = tid >> 8;        // kv-group
  const int tl = tid & 255;      // tid within group
  const int wl = tl >> 6;        // wave within group
  const int wq = w & 3;          // q-chunk

  // 64 KB blob: per group g (u16 offset g*16384): K0@0 K1@4096 V0@8192 V1@12288
  __shared__ __align__(16) u16 SM[32768];

  const size_t qkbase = ((size_t)(bh >> 4) * S) * D + (size_t)(bh & 15) * 64;
  const size_t vbase = (size_t)bh * 64 * S;  // vt[bh][d][s]

  const int q = qt * 128 + wq * 32 + l31;
  s16x8 qf[4];
#pragma unroll
  for (int ks = 0; ks < 4; ++ks)
    qf[ks] = *(const s16x8*)(qp + qkbase + (size_t)q * D + ks * 16 + l5 * 8);

  f32x16 octx[2] = {};
  float m_run = -1e30f, l_run = 0.f;
  const float C1 = 0.125f * 1.44269504088896f;  // 1/sqrt(64) * log2(e)

  auto stage = [&](int buf, int ti) {
    const int kv0 = (g * 16 + ti) * 64;
    u16* Kd = SM + g * 16384 + buf * 4096;
    u16* Vd = SM + g * 16384 + 8192 + buf * 4096;
#pragma unroll
    for (int i = 0; i < 2; ++i) {  // K tile: 512 chunks of 16B
      const int gch = i * 256 + tl;
      const int kv = gch >> 3, cc = gch & 7;
      GLDS16(kp + qkbase + (size_t)(kv0 + kv) * D + ((cc ^ (kv & 7)) << 3),
             Kd + (size_t)(i * 256 + wl * 64) * 8);
    }
#pragma unroll
    for (int i = 0; i < 2; ++i) {  // V^T tile: 512 chunks
      const int gch = i * 256 + tl;
      const int d = gch >> 3, cc = gch & 7;
      GLDS16(vt + vbase + (size_t)d * S + kv0 + ((cc ^ (d & 7)) << 3),
             Vd + (size_t)(i * 256 + wl * 64) * 8);
    }
  };

  stage(0, 0);
  const int NT = 16;  // tiles per group
  for (int t = 0; t < NT; ++t) {
    __syncthreads();  // tile-t loads drained; prev readers done with buf
    if (t + 1 < NT) stage((t + 1) & 1, t + 1);
    const u16* Kb = SM + g * 16384 + (t & 1) * 4096;
    const u16* Vb = SM + g * 16384 + 8192 + (t & 1) * 4096;

    // ---- scores^T: sc[fk], rows kv (32 each), cols q ----
    f32x16 sc[2] = {};
#pragma unroll
    for (int ks = 0; ks < 4; ++ks) {
      __builtin_amdgcn_s_setprio(1);
#pragma unroll
      for (int fk = 0; fk < 2; ++fk) {
        const int kv = fk * 32 + l31;
        const int c = (ks << 1) + l5;
        const s16x8 kf =
            *(const s16x8*)(Kb + (size_t)(kv * 8 + (c ^ (kv & 7))) * 8);
        sc[fk] = __builtin_amdgcn_mfma_f32_32x32x16_bf16(kf, qf[ks], sc[fk],
                                                         0, 0, 0);
      }
      __builtin_amdgcn_s_setprio(0);
    }

    // ---- online softmax (log2 domain), tree reductions ----
    float tv[16];
#pragma unroll
    for (int r = 0; r < 16; ++r) tv[r] = fmaxf(sc[0][r], sc[1][r]);
#pragma unroll
    for (int r = 0; r < 8; ++r) tv[r] = fmaxf(tv[r], tv[r + 8]);
#pragma unroll
    for (int r = 0; r < 4; ++r) tv[r] = fmaxf(tv[r], tv[r + 4]);
    float mt = fmaxf(fmaxf(tv[0], tv[1]), fmaxf(tv[2], tv[3]));
    mt = fmaxf(mt, __shfl_xor(mt, 32, 64));
    mt *= C1;
    if (!__all(mt - m_run <= 11.5f)) {  // defer-max (T13)
      const float mnew = fmaxf(m_run, mt);
      const float resc = __builtin_amdgcn_exp2f(m_run - mnew);
      m_run = mnew;
      l_run *= resc;
#pragma unroll
      for (int fd = 0; fd < 2; ++fd)
#pragma unroll
        for (int r = 0; r < 16; ++r) octx[fd][r] *= resc;
    }
#pragma unroll
    for (int fk = 0; fk < 2; ++fk)
#pragma unroll
      for (int r = 0; r < 16; ++r)
        sc[fk][r] = __builtin_amdgcn_exp2f(fmaf(sc[fk][r], C1, -m_run));
    float sv[16];
#pragma unroll
    for (int r = 0; r < 16; ++r) sv[r] = sc[0][r] + sc[1][r];
#pragma unroll
    for (int r = 0; r < 8; ++r) sv[r] += sv[r + 8];
#pragma unroll
    for (int r = 0; r < 4; ++r) sv[r] += sv[r + 4];
    float rsum = (sv[0] + sv[1]) + (sv[2] + sv[3]);
    rsum += __shfl_xor(rsum, 32, 64);
    l_run += rsum;

    // ---- PV: octx[fd] += mfma32(V^T frag, P B-frag); T12 permlane path ----
#pragma unroll
    for (int fk = 0; fk < 2; ++fk) {
#pragma unroll
      for (int hf = 0; hf < 2; ++hf) {
        u32 x0, x1, y0, y1;
        asm("v_cvt_pk_bf16_f32 %0, %1, %2"
            : "=v"(x0)
            : "v"(sc[fk][hf * 8 + 0]), "v"(sc[fk][hf * 8 + 1]));
        asm("v_cvt_pk_bf16_f32 %0, %1, %2"
            : "=v"(x1)
            : "v"(sc[fk][hf * 8 + 2]), "v"(sc[fk][hf * 8 + 3]));
        asm("v_cvt_pk_bf16_f32 %0, %1, %2"
            : "=v"(y0)
            : "v"(sc[fk][hf * 8 + 4]), "v"(sc[fk][hf * 8 + 5]));
        asm("v_cvt_pk_bf16_f32 %0, %1, %2"
            : "=v"(y1)
            : "v"(sc[fk][hf * 8 + 6]), "v"(sc[fk][hf * 8 + 7]));
        asm("v_permlane32_swap_b32 %0, %1" : "+v"(x0), "+v"(y0));
        asm("v_permlane32_swap_b32 %0, %1" : "+v"(x1), "+v"(y1));
        u32x4 bw;
        bw[0] = x0; bw[1] = x1; bw[2] = y0; bw[3] = y1;
        const s16x8 pb = __builtin_bit_cast(s16x8, bw);
        const int tc = fk * 2 + hf;  // 16-kv chunk 0..3
        __builtin_amdgcn_s_setprio(1);
#pragma unroll
        for (int fd = 0; fd < 2; ++fd) {
          const int d = fd * 32 + l31;
          const int c = (tc << 1) + l5;
          const s16x8 vf =
              *(const s16x8*)(Vb + (size_t)(d * 8 + (c ^ (d & 7))) * 8);
          octx[fd] = __builtin_amdgcn_mfma_f32_32x32x16_bf16(vf, pb, octx[fd],
                                                             0, 0, 0);
        }
        __builtin_amdgcn_s_setprio(0);
      }
    }
  }

  // ---- merge the two kv-groups' states, then finalize ----
  __syncthreads();  // all compute reads of SM done
  float* scr = (float*)(void*)SM;  // scratch: [wq][lane][34] f32 = 34 KB
  if (w >= 4) {
    float* dst = scr + ((size_t)wq * 64 + lane) * 34;
#pragma unroll
    for (int fd = 0; fd < 2; ++fd)
#pragma unroll
      for (int r = 0; r < 16; ++r) dst[fd * 16 + r] = octx[fd][r];
    dst[32] = m_run;
    dst[33] = l_run;
  }
  __syncthreads();
  if (w < 4) {
    const float* src = scr + ((size_t)wq * 64 + lane) * 34;
    const float m1 = src[32], l1 = src[33];
    const float mm = fmaxf(m_run, m1);
    const float r0 = __builtin_amdgcn_exp2f(m_run - mm);
    const float r1 = __builtin_amdgcn_exp2f(m1 - mm);
    const float linv = 1.f / (l_run * r0 + l1 * r1);
#pragma unroll
    for (int fd = 0; fd < 2; ++fd)
#pragma unroll
      for (int gg = 0; gg < 4; ++gg) {
        // reg = gg*4 + j -> d = fd*32 + gg*8 + l5*4 + j
        ushort4 o;
        o.x = bf16_rne((octx[fd][gg * 4 + 0] * r0 + src[fd * 16 + gg * 4 + 0] * r1) * linv);
        o.y = bf16_rne((octx[fd][gg * 4 + 1] * r0 + src[fd * 16 + gg * 4 + 1] * r1) * linv);
        o.z = bf16_rne((octx[fd][gg * 4 + 2] * r0 + src[fd * 16 + gg * 4 + 2] * r1) * linv);
        o.w = bf16_rne((octx[fd][gg * 4 + 3] * r0 + src[fd * 16 + gg * 4 + 3] * r1) * linv);
        *(ushort4*)(ctx + qkbase + (size_t)q * D + fd * 32 + gg * 8 + l5 * 4) =
            o;
      }
  }
}

// ---------------- launcher ----------------
extern "C" void kernel_launch(void* const* d_in, const int* in_sizes, int n_in,
                              void* d_out, int out_size, void* d_ws,
                              size_t ws_size, hipStream_t stream) {
  (void)in_sizes; (void)n_in; (void)out_size;
  const float* Q = (const float*)d_in[0];
  const float* K = (const float*)d_in[1];
  const float* V = (const float*)d_in[2];
  const float* Wq = (const float*)d_in[3];
  const float* bq = (const float*)d_in[4];
  const float* bk = (const float*)d_in[6];
  const float* Wk = (const float*)d_in[5];
  const float* Wv = (const float*)d_in[7];
  const float* bv = (const float*)d_in[8];
  const float* Wo = (const float*)d_in[9];
  const float* bo = (const float*)d_in[10];

  const int B = 2, S = 2048, D = 1024, H = 16;
  const int M = B * S;              // 4096
  const size_t NE = (size_t)M * D;  // 4M elems
  const size_t WE = (size_t)D * D;  // 1M elems

  const int n4 = (int)(NE / 4), nb = (n4 + 255) / 256;
  const int w4 = (int)(WE / 4), wb = (w4 + 255) / 256;
  dim3 gg(D / 128, M / 128, 3);  // grouped QKV
  dim3 go(D / 128, M / 128, 1);
  dim3 ga(B * H, S / 128);  // (32, 16): bh fastest -> per-head XCD affinity

  const bool big = ws_size >= (size_t)(6 * NE + 4 * WE) * 2;

  if (big) {
    u16* B0 = (u16*)d_ws;  // Qb, later ctx
    u16* B1 = B0 + NE;     // Kb
    u16* B2 = B1 + NE;     // Vb
    u16* B3 = B2 + NE;     // qp
    u16* B4 = B3 + NE;     // kp
    u16* B5 = B4 + NE;     // vt  [b][h][d][s]
    u16* Wqb = B5 + NE;
    u16* Wkb = Wqb + WE;
    u16* Wvb = Wkb + WE;
    u16* Wob = Wvb + WE;

    cvt4_kernel<<<dim3(nb, 3), 256, 0, stream>>>(Q, K, V, nullptr, B0, B1, B2,
                                                 nullptr, n4);
    cvt4_kernel<<<dim3(wb, 4), 256, 0, stream>>>(Wq, Wk, Wv, Wo, Wqb, Wkb, Wvb,
                                                 Wob, w4);
    gemm128<1, 1><<<gg, 256, 0, stream>>>(B0, B1, B2, Wqb, Wkb, Wvb, bq, bk,
                                          bv, B3, B4, B5, M, D, D);
    attn_fused<<<ga, 512, 0, stream>>>(B3, B4, B5, B0);
    gemm128<0, 0><<<go, 256, 0, stream>>>(B0, B0, B0, Wob, Wob, Wob, bo, bo,
                                          bo, d_out, d_out, d_out, M, D, D);
  } else {
    // fallback: sequential projections, 4 activation buffers, no in-place use
    u16* B0 = (u16*)d_ws;  // Qb -> later kp
    u16* B1 = B0 + NE;     // Kb -> later vt
    u16* B2 = B1 + NE;     // Vb -> later ctx
    u16* B3 = B2 + NE;     // qp
    u16* Wqb = B3 + NE;
    u16* Wkb = Wqb + WE;
    u16* Wvb = Wkb + WE;
    u16* Wob = Wvb + WE;

    cvt4_kernel<<<dim3(nb, 3), 256, 0, stream>>>(Q, K, V, nullptr, B0, B1, B2,
                                                 nullptr, n4);
    cvt4_kernel<<<dim3(wb, 4), 256, 0, stream>>>(Wq, Wk, Wv, Wo, Wqb, Wkb, Wvb,
                                                 Wob, w4);
    gemm128<1, 0><<<go, 256, 0, stream>>>(B0, B0, B0, Wqb, Wqb, Wqb, bq, bq,
                                          bq, B3, B3, B3, M, D, D);  // qp<-Qb
    gemm128<1, 0><<<go, 256, 0, stream>>>(B1, B1, B1, Wkb, Wkb, Wkb, bk, bk,
                                          bk, B0, B0, B0, M, D, D);  // kp<-Kb (B0 free)
    gemm128<1, 2><<<go, 256, 0, stream>>>(B2, B2, B2, Wvb, Wvb, Wvb, bv, bv,
                                          bv, B1, B1, B1, M, D, D);  // vt<-Vb (B1 free)
    attn_fused<<<ga, 512, 0, stream>>>(B3, B0, B1, B2);  // ctx -> B2
    gemm128<0, 0><<<go, 256, 0, stream>>>(B2, B2, B2, Wob, Wob, Wob, bo, bo,
                                          bo, d_out, d_out, d_out, M, D, D);
  }
}